// Round 6
// baseline (395.820 us; speedup 1.0000x reference)
//
#include <hip/hip_runtime.h>
#include <hip/hip_bf16.h>

#define B_SZ 1024
#define C_SZ 100
#define D_SZ 768

#define BM 128                 // d-rows per block (M)
#define BN 256                 // b-cols per block (N)
#define BK 32                  // e per K-step
#define NKT (D_SZ / BK)        // 24
#define NTHREADS 512           // 8 waves: 2(M) x 4(N), wave tile 64x64
#define TILES_PER_CLASS 24     // 6 M-tiles x 4 N-tiles

#define AS_STRIDE 40           // ushorts: 80-B row stride -> conflict-free b128 reads
#define AS_BUF (BM * AS_STRIDE)

#define TBL_ELEMS ((size_t)C_SZ * D_SZ)
#define XN_ELEMS  ((size_t)C_SZ * B_SZ * D_SZ)

typedef float f32x4 __attribute__((ext_vector_type(4)));
typedef short short8 __attribute__((ext_vector_type(8)));

__device__ __forceinline__ ushort f2bf(float f) {
    union { __hip_bfloat16 b; ushort u; } cv; cv.b = __float2bfloat16(f); return cv.u;
}
__device__ __forceinline__ float bf2f(ushort u) {
    union { __hip_bfloat16 b; ushort us; } cv; cv.us = u; return __bfloat162float(cv.b);
}

// ---- prepass 1: rd = 1/diag, md = mean*rd ----
__global__ __launch_bounds__(256) void make_tables(const float* __restrict__ mean,
                                                   const float* __restrict__ diag,
                                                   float* __restrict__ rd,
                                                   float* __restrict__ md) {
    const int i = ((int)blockIdx.x * 256 + (int)threadIdx.x) * 4;
    if (i < (int)TBL_ELEMS) {
        const f32x4 dv = *(const f32x4*)(diag + i);
        const f32x4 mv = *(const f32x4*)(mean + i);
        f32x4 r, m;
        r.x = 1.0f / dv.x; r.y = 1.0f / dv.y; r.z = 1.0f / dv.z; r.w = 1.0f / dv.w;
        m.x = mv.x * r.x;  m.y = mv.y * r.y;  m.z = mv.z * r.z;  m.w = mv.w * r.w;
        *(f32x4*)(rd + i) = r;
        *(f32x4*)(md + i) = m;
    }
}

// ---- prepass 2: xn[c][b][d] = raw*rd - md, bf16 ----
__global__ __launch_bounds__(256) void conv_xn(const float* __restrict__ raw,
                                               const float* __restrict__ rd,
                                               const float* __restrict__ md,
                                               ushort* __restrict__ xn) {
    const int CPC = B_SZ * D_SZ / 8;
    const size_t n8 = XN_ELEMS / 8;
    for (size_t i = (size_t)blockIdx.x * 256 + threadIdx.x; i < n8;
         i += (size_t)gridDim.x * 256) {
        const int c   = (int)(i / CPC);
        const int rem = (int)(i - (size_t)c * CPC);
        const int dch = rem % (D_SZ / 8);
        const float* rp  = raw + (size_t)rem * 8;
        const float* rdp = rd + (size_t)c * D_SZ + dch * 8;
        const float* mdp = md + (size_t)c * D_SZ + dch * 8;
        const f32x4 r0 = *(const f32x4*)rp,  r1 = *(const f32x4*)(rp + 4);
        const f32x4 d0 = *(const f32x4*)rdp, d1 = *(const f32x4*)(rdp + 4);
        const f32x4 m0 = *(const f32x4*)mdp, m1 = *(const f32x4*)(mdp + 4);
        short8 p;
        p[0]=(short)f2bf(r0.x*d0.x - m0.x); p[1]=(short)f2bf(r0.y*d0.y - m0.y);
        p[2]=(short)f2bf(r0.z*d0.z - m0.z); p[3]=(short)f2bf(r0.w*d0.w - m0.w);
        p[4]=(short)f2bf(r1.x*d1.x - m1.x); p[5]=(short)f2bf(r1.y*d1.y - m1.y);
        p[6]=(short)f2bf(r1.z*d1.z - m1.z); p[7]=(short)f2bf(r1.w*d1.w - m1.w);
        *(short8*)(xn + i * 8) = p;
    }
}

// MODE 2: X frags direct from xn (bf16); MODE 0: no-ws fallback (divide on the fly)
template <int MODE>
__global__ __launch_bounds__(NTHREADS, 4) void fecam_scores(
        const float* __restrict__ raw, const float* __restrict__ mean,
        const float* __restrict__ diag, const float* __restrict__ inv,
        const ushort* __restrict__ xnAll, float* __restrict__ out) {
    __shared__ __align__(16) ushort aLds[2 * AS_BUF];   // 20.5 KB
    __shared__ float red[8 * 64];                       //  2 KB

    const int tid = (int)threadIdx.x;
    const int bx  = (int)blockIdx.x;

    // XCD-pinned class grouping (validated R3: A read from HBM ~once)
    const int x = bx & 7;
    const int slot = bx >> 3;
    const int nCls  = (x < 4) ? 13 : 12;
    const int baseC = (x < 4) ? x * 13 : 52 + (x - 4) * 12;
    const int ci = slot / TILES_PER_CLASS;
    if (ci >= nCls) return;
    const int t  = slot % TILES_PER_CLASS;
    const int c  = baseC + ci;
    const int d0 = (t >> 2) * BM;
    const int b0 = (t & 3) * BN;

    const int lane = tid & 63;
    const int wid  = tid >> 6;
    const int wm   = wid >> 2;
    const int wn   = wid & 3;
    const int l15  = lane & 15;
    const int l4   = lane >> 4;

    const float*  Af  = inv + (size_t)c * D_SZ * D_SZ;
    const ushort* xnc = xnAll + (size_t)c * B_SZ * D_SZ;

    // A stage: thread covers row r = tid>>2, 8 f32 at chunk (tid&3)
    const int ar_row = tid >> 2;
    const int ar_ch  = tid & 3;
    const float* agp = Af + (size_t)(d0 + ar_row) * D_SZ + ar_ch * 8;
    ushort* adst = aLds + ar_row * AS_STRIDE + ar_ch * 8;

    auto load_a = [&](f32x4& a0, f32x4& a1, int kt) {
        const float* gp = agp + kt * BK;
        a0 = *(const f32x4*)gp;
        a1 = *(const f32x4*)(gp + 4);
    };
    auto write_a = [&](int buf, const f32x4& a0, const f32x4& a1) {
        short8 p;
        p[0]=(short)f2bf(a0.x); p[1]=(short)f2bf(a0.y); p[2]=(short)f2bf(a0.z); p[3]=(short)f2bf(a0.w);
        p[4]=(short)f2bf(a1.x); p[5]=(short)f2bf(a1.y); p[6]=(short)f2bf(a1.z); p[7]=(short)f2bf(a1.w);
        *(short8*)(adst + buf * AS_BUF) = p;
    };
    auto load_xf = [&](short8* xf, int kt) {
        const int k0 = kt * BK;
        #pragma unroll
        for (int n = 0; n < 4; ++n) {
            const int bl = b0 + wn * 64 + n * 16 + l15;
            if constexpr (MODE == 2) {
                xf[n] = *(const short8*)(xnc + (size_t)bl * D_SZ + k0 + l4 * 8);
            } else {
                const float* rp = raw + (size_t)bl * D_SZ + k0 + l4 * 8;
                const f32x4 r0 = *(const f32x4*)rp, r1 = *(const f32x4*)(rp + 4);
                const f32x4 mm0 = *(const f32x4*)(mean + (size_t)c * D_SZ + k0 + l4 * 8);
                const f32x4 mm1 = *(const f32x4*)(mean + (size_t)c * D_SZ + k0 + l4 * 8 + 4);
                const f32x4 gg0 = *(const f32x4*)(diag + (size_t)c * D_SZ + k0 + l4 * 8);
                const f32x4 gg1 = *(const f32x4*)(diag + (size_t)c * D_SZ + k0 + l4 * 8 + 4);
                short8 p;
                p[0]=(short)f2bf((r0.x-mm0.x)/gg0.x); p[1]=(short)f2bf((r0.y-mm0.y)/gg0.y);
                p[2]=(short)f2bf((r0.z-mm0.z)/gg0.z); p[3]=(short)f2bf((r0.w-mm0.w)/gg0.w);
                p[4]=(short)f2bf((r1.x-mm1.x)/gg1.x); p[5]=(short)f2bf((r1.y-mm1.y)/gg1.y);
                p[6]=(short)f2bf((r1.z-mm1.z)/gg1.z); p[7]=(short)f2bf((r1.w-mm1.w)/gg1.w);
                xf[n] = p;
            }
        }
    };

    f32x4 acc[4][4] = {};

    auto mfma_block = [&](int buf, const short8* xf) {
        const ushort* ab = aLds + buf * AS_BUF;
        #pragma unroll
        for (int m = 0; m < 4; ++m) {
            const short8 af = *(const short8*)(ab + (wm * 64 + m * 16 + l15) * AS_STRIDE + l4 * 8);
            #pragma unroll
            for (int n = 0; n < 4; ++n)
                acc[m][n] = __builtin_amdgcn_mfma_f32_16x16x32_bf16(af, xf[n], acc[m][n], 0, 0, 0);
        }
    };

    // prologue: buffer 0 + first X frags
    {
        f32x4 a0, a1;
        load_a(a0, a1, 0);
        write_a(0, a0, a1);
    }
    short8 xfA[4], xfB[4];
    load_xf(xfA, 0);
    __syncthreads();

    for (int kt = 0; kt < NKT; kt += 2) {
        f32x4 a0, a1;
        // even step: compute buf0/xfA, stage kt+1 -> buf1/xfB
        load_a(a0, a1, kt + 1);
        load_xf(xfB, kt + 1);
        mfma_block(0, xfA);
        write_a(1, a0, a1);
        __syncthreads();
        // odd step: compute buf1/xfB, stage kt+2 -> buf0/xfA
        if (kt + 2 < NKT) {
            load_a(a0, a1, kt + 2);
            load_xf(xfA, kt + 2);
        }
        mfma_block(1, xfB);
        if (kt + 2 < NKT) {
            write_a(0, a0, a1);
        }
        __syncthreads();
    }

    // ---- fold: v[n] = sum_d temp'[d,b] * x[b,d] ----
    // C/D layout (validated): col(b)=l15, row(d)=l4*4+j
    float v[4] = {};
    #pragma unroll
    for (int m = 0; m < 4; ++m) {
        const int dd = d0 + wm * 64 + m * 16 + l4 * 4;
        #pragma unroll
        for (int n = 0; n < 4; ++n) {
            const int bl = b0 + wn * 64 + n * 16 + l15;
            float xv[4];
            if constexpr (MODE == 2) {
                const ushort4 x4 = *(const ushort4*)(xnc + (size_t)bl * D_SZ + dd);
                xv[0]=bf2f(x4.x); xv[1]=bf2f(x4.y); xv[2]=bf2f(x4.z); xv[3]=bf2f(x4.w);
            } else {
                const f32x4 rv = *(const f32x4*)(raw + (size_t)bl * D_SZ + dd);
                const f32x4 mm4 = *(const f32x4*)(mean + (size_t)c * D_SZ + dd);
                const f32x4 gg4 = *(const f32x4*)(diag + (size_t)c * D_SZ + dd);
                xv[0]=(rv.x-mm4.x)/gg4.x; xv[1]=(rv.y-mm4.y)/gg4.y;
                xv[2]=(rv.z-mm4.z)/gg4.z; xv[3]=(rv.w-mm4.w)/gg4.w;
            }
            v[n] += acc[m][n][0]*xv[0] + acc[m][n][1]*xv[1]
                  + acc[m][n][2]*xv[2] + acc[m][n][3]*xv[3];
        }
    }
    #pragma unroll
    for (int n = 0; n < 4; ++n) {
        v[n] += __shfl_xor(v[n], 16);
        v[n] += __shfl_xor(v[n], 32);
    }
    if (lane < 16) {
        #pragma unroll
        for (int n = 0; n < 4; ++n) red[wid * 64 + n * 16 + l15] = v[n];
    }
    __syncthreads();
    if (tid < BN) {
        const int wno = tid >> 6;
        const int off = tid & 63;
        const float p = red[wno * 64 + off] + red[(4 + wno) * 64 + off];
        atomicAdd(out + (size_t)(b0 + tid) * C_SZ + c, -p);
    }
}

extern "C" void kernel_launch(void* const* d_in, const int* in_sizes, int n_in,
                              void* d_out, int out_size, void* d_ws, size_t ws_size,
                              hipStream_t stream) {
    const float* raw  = (const float*)d_in[0];
    const float* mean = (const float*)d_in[1];
    const float* inv  = (const float*)d_in[2];
    const float* diag = (const float*)d_in[3];
    float* out = (float*)d_out;

    const size_t TBL_B = TBL_ELEMS * 4;
    const size_t XN_B  = XN_ELEMS * 2;          // 157,286,400
    const size_t need  = 2 * TBL_B + XN_B;      // ~157.9 MB

    hipMemsetAsync(d_out, 0, (size_t)out_size * sizeof(float), stream);
    dim3 grid(8 * 13 * TILES_PER_CLASS);        // 2496

    if (ws_size >= need) {
        float*  rdT = (float*)d_ws;
        float*  mdT = (float*)((char*)d_ws + TBL_B);
        ushort* xn  = (ushort*)((char*)d_ws + 2 * TBL_B);
        make_tables<<<75, 256, 0, stream>>>(mean, diag, rdT, mdT);
        conv_xn<<<2048, 256, 0, stream>>>(raw, rdT, mdT, xn);
        fecam_scores<2><<<grid, NTHREADS, 0, stream>>>(raw, mean, diag, inv, xn, out);
    } else {
        fecam_scores<0><<<grid, NTHREADS, 0, stream>>>(raw, mean, diag, inv, nullptr, out);
    }
}

// Round 7
// 346.440 us; speedup vs baseline: 1.1425x; 1.1425x over previous
//
#include <hip/hip_runtime.h>
#include <hip/hip_bf16.h>

#define B_SZ 1024
#define C_SZ 100
#define D_SZ 768

#define BM 128                 // d-rows per block (M)
#define BN 256                 // b-cols per block (N)
#define BK 32                  // e per K-step
#define NKT (D_SZ / BK)        // 24
#define NTHREADS 512           // 8 waves: 2(M) x 4(N), wave tile 64x64
#define TILES_PER_CLASS 24     // 6 M-tiles x 4 N-tiles

#define A_HALF (BM * BK)       // 4096 ushorts = 8 KB / buffer
#define X_HALF (BN * BK)       // 8192 ushorts = 16 KB / buffer

#define TBL_ELEMS ((size_t)C_SZ * D_SZ)          // 76,800
#define AP_ELEMS  ((size_t)C_SZ * D_SZ * D_SZ)   // 58,982,400
#define RB_ELEMS  ((size_t)B_SZ * D_SZ)          // 786,432

typedef float f32x4 __attribute__((ext_vector_type(4)));
typedef short short8 __attribute__((ext_vector_type(8)));

__device__ __forceinline__ ushort f2bf(float f) {
    union { __hip_bfloat16 b; ushort u; } cv; cv.b = __float2bfloat16(f); return cv.u;
}
__device__ __forceinline__ float bf2f(ushort u) {
    union { __hip_bfloat16 b; ushort us; } cv; cv.us = u; return __bfloat162float(cv.b);
}
__device__ __forceinline__ void gload_lds16(const void* g, void* l) {
    __builtin_amdgcn_global_load_lds((const __attribute__((address_space(1))) void*)g,
                                     (__attribute__((address_space(3))) void*)l, 16, 0, 0);
}

// ---- prepass 1: rd = 1/diag, md = mean*rd ----
__global__ __launch_bounds__(256) void make_tables(const float* __restrict__ mean,
                                                   const float* __restrict__ diag,
                                                   float* __restrict__ rd,
                                                   float* __restrict__ md) {
    const int i = ((int)blockIdx.x * 256 + (int)threadIdx.x) * 4;
    if (i < (int)TBL_ELEMS) {
        const f32x4 dv = *(const f32x4*)(diag + i);
        const f32x4 mv = *(const f32x4*)(mean + i);
        f32x4 r, m;
        r.x = 1.0f / dv.x; r.y = 1.0f / dv.y; r.z = 1.0f / dv.z; r.w = 1.0f / dv.w;
        m.x = mv.x * r.x;  m.y = mv.y * r.y;  m.z = mv.z * r.z;  m.w = mv.w * r.w;
        *(f32x4*)(rd + i) = r;
        *(f32x4*)(md + i) = m;
    }
}

// ---- prepass 2: rawbf = bf16(raw) ----
__global__ __launch_bounds__(256) void conv_rawbf(const float* __restrict__ raw,
                                                  ushort* __restrict__ rb) {
    const size_t i = (size_t)blockIdx.x * 256 + threadIdx.x;   // 98304 chunks of 8
    const f32x4 v0 = *(const f32x4*)(raw + i * 8);
    const f32x4 v1 = *(const f32x4*)(raw + i * 8 + 4);
    short8 p;
    p[0]=(short)f2bf(v0.x); p[1]=(short)f2bf(v0.y); p[2]=(short)f2bf(v0.z); p[3]=(short)f2bf(v0.w);
    p[4]=(short)f2bf(v1.x); p[5]=(short)f2bf(v1.y); p[6]=(short)f2bf(v1.z); p[7]=(short)f2bf(v1.w);
    *(short8*)(rb + i * 8) = p;
}

// ---- prepass 3: A'[c][d][e] = bf16(A*rd_c[e]); w[c][d] = dot(A_row, md_c) ----
// one wave per A row; fuses the w reduction into the (mandatory) A read.
__global__ __launch_bounds__(512) void conv_aprime(const float* __restrict__ inv,
                                                   const float* __restrict__ rd,
                                                   const float* __restrict__ md,
                                                   ushort* __restrict__ ap,
                                                   float* __restrict__ w) {
    const int lane = (int)threadIdx.x & 63;
    const int wv   = (int)threadIdx.x >> 6;
    const int ridx = (int)blockIdx.x * 8 + wv;            // 0..76799 = c*768+d
    const int c    = ridx / D_SZ;
    const float* arow = inv + (size_t)ridx * D_SZ;
    const float* rdc  = rd + (size_t)c * D_SZ;
    const float* mdc  = md + (size_t)c * D_SZ;
    ushort* aprow = ap + (size_t)ridx * D_SZ;
    float dot = 0.f;
    #pragma unroll
    for (int j = 0; j < 3; ++j) {
        const int e = j * 256 + lane * 4;
        const f32x4 a  = *(const f32x4*)(arow + e);
        const f32x4 r4 = *(const f32x4*)(rdc + e);
        const f32x4 m4 = *(const f32x4*)(mdc + e);
        dot += a.x * m4.x + a.y * m4.y + a.z * m4.z + a.w * m4.w;
        ushort4 p;
        p.x = f2bf(a.x * r4.x); p.y = f2bf(a.y * r4.y);
        p.z = f2bf(a.z * r4.z); p.w = f2bf(a.w * r4.w);
        *(ushort4*)(aprow + e) = p;
    }
    #pragma unroll
    for (int k = 1; k < 64; k <<= 1) dot += __shfl_xor(dot, k);
    if (lane == 0) w[ridx] = dot;
}

// ---- prepass 4: out[b][c] = u_c . raw[b] - s_c   (u = w*rd, s = w.md) ----
__global__ __launch_bounds__(256) void seed_out(const float* __restrict__ raw,
                                                const float* __restrict__ rd,
                                                const float* __restrict__ md,
                                                const float* __restrict__ w,
                                                float* __restrict__ out) {
    __shared__ float uS[D_SZ];
    __shared__ float sred[4];
    const int tid = (int)threadIdx.x;
    const int c   = (int)blockIdx.x;
    const float* wc  = w + (size_t)c * D_SZ;
    const float* rdc = rd + (size_t)c * D_SZ;
    const float* mdc = md + (size_t)c * D_SZ;
    float sp = 0.f;
    for (int d = tid; d < D_SZ; d += 256) {
        const float wv = wc[d];
        uS[d] = wv * rdc[d];
        sp += wv * mdc[d];
    }
    #pragma unroll
    for (int k = 1; k < 64; k <<= 1) sp += __shfl_xor(sp, k);
    if ((tid & 63) == 0) sred[tid >> 6] = sp;
    __syncthreads();
    const float s = sred[0] + sred[1] + sred[2] + sred[3];
    for (int b = tid; b < B_SZ; b += 256) {
        const float* rrow = raw + (size_t)b * D_SZ;
        float dot = 0.f;
        #pragma unroll 4
        for (int j = 0; j < D_SZ / 4; ++j) {
            const f32x4 rv = *(const f32x4*)(rrow + j * 4);
            dot += rv.x * uS[j*4] + rv.y * uS[j*4+1] + rv.z * uS[j*4+2] + rv.w * uS[j*4+3];
        }
        out[(size_t)b * C_SZ + c] = dot - s;   // term2v; main adds -foldsum
    }
}

// MODE 2: A' gload_lds + rawbf gload_lds; fold x = raw*rd - md (f32)
// MODE 0: no ws — reg-staged A f32->bf16, X=(raw-mean)/diag; full dist in-kernel
template <int MODE>
__global__ __launch_bounds__(NTHREADS, 4) void fecam_scores(
        const float* __restrict__ raw, const float* __restrict__ mean,
        const float* __restrict__ diag, const float* __restrict__ inv,
        const float* __restrict__ rdT, const float* __restrict__ mdT,
        const ushort* __restrict__ apAll, const ushort* __restrict__ rbAll,
        float* __restrict__ out) {
    __shared__ __align__(16) ushort aLds[2 * A_HALF];   // 16 KB
    __shared__ __align__(16) ushort xLds[2 * X_HALF];   // 32 KB
    __shared__ float red[8 * 64];                       //  2 KB

    const int tid = (int)threadIdx.x;
    const int bx  = (int)blockIdx.x;

    // XCD-pinned class grouping (validated R3: A read from HBM ~once)
    const int x = bx & 7;
    const int slot = bx >> 3;
    const int nCls  = (x < 4) ? 13 : 12;
    const int baseC = (x < 4) ? x * 13 : 52 + (x - 4) * 12;
    const int ci = slot / TILES_PER_CLASS;
    if (ci >= nCls) return;
    const int t  = slot % TILES_PER_CLASS;
    const int c  = baseC + ci;
    const int d0 = (t >> 2) * BM;
    const int b0 = (t & 3) * BN;

    const int lane = tid & 63;
    const int wid  = tid >> 6;
    const int wm   = wid >> 2;
    const int wn   = wid & 3;
    const int l15  = lane & 15;
    const int l4   = lane >> 4;

    const ushort* apc = apAll + (size_t)c * D_SZ * D_SZ;
    const float*  Af  = inv + (size_t)c * D_SZ * D_SZ;

    // ---- staging: source-side XOR swizzle q = (s&3) ^ ((r>>1)&3) ----
    // (rows are 64B apart -> bank period 2 rows; (r>>1)&3 gives free 2-way;
    //  R5's (r&3) was 4-way on even rows -> the measured 1.47e7 conflicts)
    auto stage_a = [&](ushort* dst, int kt) {
        const int s = tid;                    // 512 slots: 128 rows x 4 chunks
        const int r = s >> 2;
        const int q = (s & 3) ^ ((r >> 1) & 3);
        if constexpr (MODE == 2) {
            gload_lds16(apc + (size_t)(d0 + r) * D_SZ + kt * BK + q * 8, dst + s * 8);
        } else {
            const float* gp = Af + (size_t)(d0 + r) * D_SZ + kt * BK + q * 8;
            const f32x4 a0 = *(const f32x4*)gp;
            const f32x4 a1 = *(const f32x4*)(gp + 4);
            short8 p;
            p[0]=(short)f2bf(a0.x); p[1]=(short)f2bf(a0.y); p[2]=(short)f2bf(a0.z); p[3]=(short)f2bf(a0.w);
            p[4]=(short)f2bf(a1.x); p[5]=(short)f2bf(a1.y); p[6]=(short)f2bf(a1.z); p[7]=(short)f2bf(a1.w);
            *(short8*)(dst + s * 8) = p;
        }
    };
    auto stage_x = [&](ushort* dst, int kt) {
        #pragma unroll
        for (int i = 0; i < 2; ++i) {
            const int s = tid + i * NTHREADS;  // 1024 slots: 256 rows x 4 chunks
            const int r = s >> 2;
            const int q = (s & 3) ^ ((r >> 1) & 3);
            const int e = kt * BK + q * 8;
            if constexpr (MODE == 2) {
                gload_lds16(rbAll + (size_t)(b0 + r) * D_SZ + e, dst + s * 8);
            } else {
                const float* rp = raw + (size_t)(b0 + r) * D_SZ + e;
                const f32x4 r0 = *(const f32x4*)rp, r1 = *(const f32x4*)(rp + 4);
                const f32x4 mm0 = *(const f32x4*)(mean + (size_t)c * D_SZ + e);
                const f32x4 mm1 = *(const f32x4*)(mean + (size_t)c * D_SZ + e + 4);
                const f32x4 gg0 = *(const f32x4*)(diag + (size_t)c * D_SZ + e);
                const f32x4 gg1 = *(const f32x4*)(diag + (size_t)c * D_SZ + e + 4);
                short8 p;
                p[0]=(short)f2bf((r0.x-mm0.x)/gg0.x); p[1]=(short)f2bf((r0.y-mm0.y)/gg0.y);
                p[2]=(short)f2bf((r0.z-mm0.z)/gg0.z); p[3]=(short)f2bf((r0.w-mm0.w)/gg0.w);
                p[4]=(short)f2bf((r1.x-mm1.x)/gg1.x); p[5]=(short)f2bf((r1.y-mm1.y)/gg1.y);
                p[6]=(short)f2bf((r1.z-mm1.z)/gg1.z); p[7]=(short)f2bf((r1.w-mm1.w)/gg1.w);
                *(short8*)(dst + s * 8) = p;
            }
        }
    };

    stage_a(aLds, 0);
    stage_x(xLds, 0);
    __syncthreads();

    f32x4 acc[4][4] = {};   // wave 64(M) x 64(N)

    // read chunk: fch = l4 ^ ((row>>1)&3); row = base16 + l15, base16 % 8 == 0
    // -> fch = l4 ^ ((l15>>1)&3), lane-constant across all m,n fragments.
    const int fch = l4 ^ ((l15 >> 1) & 3);
    for (int kt = 0; kt < NKT; ++kt) {
        const int cur = kt & 1;
        if (kt + 1 < NKT) {
            stage_a(aLds + (cur ^ 1) * A_HALF, kt + 1);
            stage_x(xLds + (cur ^ 1) * X_HALF, kt + 1);
        }
        const ushort* ab = aLds + cur * A_HALF;
        const ushort* xb = xLds + cur * X_HALF;
        short8 xf[4];
        #pragma unroll
        for (int n = 0; n < 4; ++n)
            xf[n] = *(const short8*)(xb + ((wn * 64 + n * 16 + l15) * 4 + fch) * 8);
        #pragma unroll
        for (int m = 0; m < 4; ++m) {
            const short8 af = *(const short8*)(ab + ((wm * 64 + m * 16 + l15) * 4 + fch) * 8);
            #pragma unroll
            for (int n = 0; n < 4; ++n)
                acc[m][n] = __builtin_amdgcn_mfma_f32_16x16x32_bf16(af, xf[n], acc[m][n], 0, 0, 0);
        }
        __syncthreads();
    }

    // ---- fold: p = sum over block's d-range of G[d,b] * x[b,d] (x in f32) ----
    // C/D layout (validated): col(b)=l15, row(d)=l4*4+j
    float v[4] = {};
    #pragma unroll
    for (int m = 0; m < 4; ++m) {
        const int dd = d0 + wm * 64 + m * 16 + l4 * 4;
        f32x4 rd4, md4;
        if constexpr (MODE == 2) {
            rd4 = *(const f32x4*)(rdT + (size_t)c * D_SZ + dd);
            md4 = *(const f32x4*)(mdT + (size_t)c * D_SZ + dd);
        } else {
            const f32x4 mm4 = *(const f32x4*)(mean + (size_t)c * D_SZ + dd);
            const f32x4 gg4 = *(const f32x4*)(diag + (size_t)c * D_SZ + dd);
            rd4.x = 1.0f/gg4.x; rd4.y = 1.0f/gg4.y; rd4.z = 1.0f/gg4.z; rd4.w = 1.0f/gg4.w;
            md4.x = mm4.x*rd4.x; md4.y = mm4.y*rd4.y; md4.z = mm4.z*rd4.z; md4.w = mm4.w*rd4.w;
        }
        #pragma unroll
        for (int n = 0; n < 4; ++n) {
            const int bl = b0 + wn * 64 + n * 16 + l15;
            const f32x4 rv = *(const f32x4*)(raw + (size_t)bl * D_SZ + dd);
            v[n] += acc[m][n][0] * (rv.x * rd4.x - md4.x)
                  + acc[m][n][1] * (rv.y * rd4.y - md4.y)
                  + acc[m][n][2] * (rv.z * rd4.z - md4.z)
                  + acc[m][n][3] * (rv.w * rd4.w - md4.w);
        }
    }
    #pragma unroll
    for (int n = 0; n < 4; ++n) {
        v[n] += __shfl_xor(v[n], 16);
        v[n] += __shfl_xor(v[n], 32);
    }
    if (lane < 16) {
        #pragma unroll
        for (int n = 0; n < 4; ++n) red[wid * 64 + n * 16 + l15] = v[n];
    }
    __syncthreads();
    if (tid < BN) {
        const int wno = tid >> 6;
        const int off = tid & 63;
        const float p = red[wno * 64 + off] + red[(4 + wno) * 64 + off];
        atomicAdd(out + (size_t)(b0 + tid) * C_SZ + c, -p);
    }
}

extern "C" void kernel_launch(void* const* d_in, const int* in_sizes, int n_in,
                              void* d_out, int out_size, void* d_ws, size_t ws_size,
                              hipStream_t stream) {
    const float* raw  = (const float*)d_in[0];
    const float* mean = (const float*)d_in[1];
    const float* inv  = (const float*)d_in[2];
    const float* diag = (const float*)d_in[3];
    float* out = (float*)d_out;

    const size_t TBL_B = TBL_ELEMS * 4;                    // 307,200
    const size_t AP_B  = AP_ELEMS * 2;                     // 117,964,800
    const size_t RB_B  = RB_ELEMS * 2;                     //   1,572,864
    const size_t need  = 3 * TBL_B + AP_B + RB_B;          // ~120.5 MB

    dim3 grid(8 * 13 * TILES_PER_CLASS);                   // 2496

    if (ws_size >= need) {
        float*  rdT = (float*)d_ws;
        float*  mdT = (float*)((char*)d_ws + TBL_B);
        float*  wT  = (float*)((char*)d_ws + 2 * TBL_B);
        ushort* ap  = (ushort*)((char*)d_ws + 3 * TBL_B);
        ushort* rb  = (ushort*)((char*)d_ws + 3 * TBL_B + AP_B);
        make_tables<<<75, 256, 0, stream>>>(mean, diag, rdT, mdT);
        conv_rawbf<<<384, 256, 0, stream>>>(raw, rb);
        conv_aprime<<<9600, 512, 0, stream>>>(inv, rdT, mdT, ap, wT);
        seed_out<<<C_SZ, 256, 0, stream>>>(raw, rdT, mdT, wT, out);
        fecam_scores<2><<<grid, NTHREADS, 0, stream>>>(raw, mean, diag, inv,
                                                       rdT, mdT, ap, rb, out);
    } else {
        hipMemsetAsync(d_out, 0, (size_t)out_size * sizeof(float), stream);
        fecam_scores<0><<<grid, NTHREADS, 0, stream>>>(raw, mean, diag, inv,
                                                       nullptr, nullptr, nullptr, nullptr, out);
    }
}

// Round 8
// 306.944 us; speedup vs baseline: 1.2896x; 1.1287x over previous
//
#include <hip/hip_runtime.h>
#include <hip/hip_bf16.h>

#define B_SZ 1024
#define C_SZ 100
#define D_SZ 768

#define BM 256                 // d-rows per block (M)
#define BN 256                 // b-cols per block (N)
#define BK 32                  // e per K-step
#define NKT (D_SZ / BK)        // 24
#define NTHREADS 512           // 8 waves: 2(M) x 4(N), wave tile 128x64
#define TPC 12                 // tiles/class: 3 M x 4 N
#define MF 8
#define NF 4

#define A_BUF (BM * BK)        // 8192 ushorts = 16 KB per slot
#define X_BUF (BN * BK)

#define TBL_ELEMS ((size_t)C_SZ * D_SZ)          // 76,800
#define AP_ELEMS  ((size_t)C_SZ * D_SZ * D_SZ)   // 58,982,400
#define RB_ELEMS  ((size_t)B_SZ * D_SZ)          // 786,432

typedef float f32x4 __attribute__((ext_vector_type(4)));
typedef short short8 __attribute__((ext_vector_type(8)));

__device__ __forceinline__ ushort f2bf(float f) {
    union { __hip_bfloat16 b; ushort u; } cv; cv.b = __float2bfloat16(f); return cv.u;
}
__device__ __forceinline__ float bf2f(ushort u) {
    union { __hip_bfloat16 b; ushort us; } cv; cv.us = u; return __bfloat162float(cv.b);
}
__device__ __forceinline__ void gload_lds16(const void* g, void* l) {
    __builtin_amdgcn_global_load_lds((const __attribute__((address_space(1))) void*)g,
                                     (__attribute__((address_space(3))) void*)l, 16, 0, 0);
}

// ---- prepass 1: rd = 1/diag, md = mean*rd ----
__global__ __launch_bounds__(256) void make_tables(const float* __restrict__ mean,
                                                   const float* __restrict__ diag,
                                                   float* __restrict__ rd,
                                                   float* __restrict__ md) {
    const int i = ((int)blockIdx.x * 256 + (int)threadIdx.x) * 4;
    if (i < (int)TBL_ELEMS) {
        const f32x4 dv = *(const f32x4*)(diag + i);
        const f32x4 mv = *(const f32x4*)(mean + i);
        f32x4 r, m;
        r.x = 1.0f / dv.x; r.y = 1.0f / dv.y; r.z = 1.0f / dv.z; r.w = 1.0f / dv.w;
        m.x = mv.x * r.x;  m.y = mv.y * r.y;  m.z = mv.z * r.z;  m.w = mv.w * r.w;
        *(f32x4*)(rd + i) = r;
        *(f32x4*)(md + i) = m;
    }
}

// ---- prepass 2: rawbf = bf16(raw) ----
__global__ __launch_bounds__(256) void conv_rawbf(const float* __restrict__ raw,
                                                  ushort* __restrict__ rb) {
    const size_t i = (size_t)blockIdx.x * 256 + threadIdx.x;
    const f32x4 v0 = *(const f32x4*)(raw + i * 8);
    const f32x4 v1 = *(const f32x4*)(raw + i * 8 + 4);
    short8 p;
    p[0]=(short)f2bf(v0.x); p[1]=(short)f2bf(v0.y); p[2]=(short)f2bf(v0.z); p[3]=(short)f2bf(v0.w);
    p[4]=(short)f2bf(v1.x); p[5]=(short)f2bf(v1.y); p[6]=(short)f2bf(v1.z); p[7]=(short)f2bf(v1.w);
    *(short8*)(rb + i * 8) = p;
}

// ---- prepass 3: A'[c][d][e] = bf16(A*rd_c[e]); w[c][d] = dot(A_row, md_c) ----
__global__ __launch_bounds__(512) void conv_aprime(const float* __restrict__ inv,
                                                   const float* __restrict__ rd,
                                                   const float* __restrict__ md,
                                                   ushort* __restrict__ ap,
                                                   float* __restrict__ w) {
    const int lane = (int)threadIdx.x & 63;
    const int wv   = (int)threadIdx.x >> 6;
    const int ridx = (int)blockIdx.x * 8 + wv;            // c*768+d
    const int c    = ridx / D_SZ;
    const float* arow = inv + (size_t)ridx * D_SZ;
    const float* rdc  = rd + (size_t)c * D_SZ;
    const float* mdc  = md + (size_t)c * D_SZ;
    ushort* aprow = ap + (size_t)ridx * D_SZ;
    float dot = 0.f;
    #pragma unroll
    for (int j = 0; j < 3; ++j) {
        const int e = j * 256 + lane * 4;
        const f32x4 a  = *(const f32x4*)(arow + e);
        const f32x4 r4 = *(const f32x4*)(rdc + e);
        const f32x4 m4 = *(const f32x4*)(mdc + e);
        dot += a.x * m4.x + a.y * m4.y + a.z * m4.z + a.w * m4.w;
        ushort4 p;
        p.x = f2bf(a.x * r4.x); p.y = f2bf(a.y * r4.y);
        p.z = f2bf(a.z * r4.z); p.w = f2bf(a.w * r4.w);
        *(ushort4*)(aprow + e) = p;
    }
    #pragma unroll
    for (int k = 1; k < 64; k <<= 1) dot += __shfl_xor(dot, k);
    if (lane == 0) w[ridx] = dot;
}

// ---- prepass 4: out[b][c] = u_c . raw[b] - s_c  (u = w*rd, s = w.md) ----
// 400 blocks: bx = c*4 + bchunk, each block covers 256 b rows (1 per thread)
__global__ __launch_bounds__(256) void seed_out(const float* __restrict__ raw,
                                                const float* __restrict__ rd,
                                                const float* __restrict__ md,
                                                const float* __restrict__ w,
                                                float* __restrict__ out) {
    __shared__ float uS[D_SZ];
    __shared__ float sred[4];
    const int tid = (int)threadIdx.x;
    const int c   = (int)blockIdx.x >> 2;
    const int b   = ((int)blockIdx.x & 3) * 256 + tid;
    const float* wc  = w + (size_t)c * D_SZ;
    const float* rdc = rd + (size_t)c * D_SZ;
    const float* mdc = md + (size_t)c * D_SZ;
    float sp = 0.f;
    for (int d = tid; d < D_SZ; d += 256) {
        const float wv = wc[d];
        uS[d] = wv * rdc[d];
        sp += wv * mdc[d];
    }
    #pragma unroll
    for (int k = 1; k < 64; k <<= 1) sp += __shfl_xor(sp, k);
    if ((tid & 63) == 0) sred[tid >> 6] = sp;
    __syncthreads();
    const float s = sred[0] + sred[1] + sred[2] + sred[3];
    const float* rrow = raw + (size_t)b * D_SZ;
    float dot = 0.f;
    #pragma unroll 4
    for (int j = 0; j < D_SZ / 4; ++j) {
        const f32x4 rv = *(const f32x4*)(rrow + j * 4);
        dot += rv.x * uS[j*4] + rv.y * uS[j*4+1] + rv.z * uS[j*4+2] + rv.w * uS[j*4+3];
    }
    out[(size_t)b * C_SZ + c] = dot - s;   // term2; main adds -fold
}

// MODE 2: A'/rawbf gload_lds, triple-buffer + counted vmcnt; fold x = raw*rd-md
// MODE 0: no-ws fallback: reg-staged (divides), __syncthreads triple-buffer
template <int MODE>
__global__ __launch_bounds__(NTHREADS, 2) void fecam_scores(
        const float* __restrict__ raw, const float* __restrict__ mean,
        const float* __restrict__ diag, const float* __restrict__ inv,
        const float* __restrict__ rdT, const float* __restrict__ mdT,
        const ushort* __restrict__ apAll, const ushort* __restrict__ rbAll,
        float* __restrict__ out) {
    __shared__ __align__(16) ushort aLds[3 * A_BUF];   // 48 KB
    __shared__ __align__(16) ushort xLds[3 * X_BUF];   // 48 KB
    __shared__ float red[8 * 64];                      //  2 KB

    const int tid = (int)threadIdx.x;
    const int bx  = (int)blockIdx.x;

    // XCD-pinned class grouping (validated R3)
    const int x = bx & 7;
    const int slot0 = bx >> 3;
    const int nCls  = (x < 4) ? 13 : 12;
    const int baseC = (x < 4) ? x * 13 : 52 + (x - 4) * 12;
    const int ci = slot0 / TPC;
    if (ci >= nCls) return;
    const int t  = slot0 % TPC;
    const int c  = baseC + ci;
    const int d0 = (t >> 2) * BM;      // 0..2
    const int b0 = (t & 3) * BN;       // 0..3

    const int lane = tid & 63;
    const int wid  = tid >> 6;
    const int wm   = wid >> 2;         // 0..1 (M: 128 rows each)
    const int wn   = wid & 3;          // 0..3 (N: 64 cols each)
    const int l15  = lane & 15;
    const int l4   = lane >> 4;

    const ushort* apc = apAll + (size_t)c * D_SZ * D_SZ;
    const float*  Af  = inv + (size_t)c * D_SZ * D_SZ;

    // staging: source-side XOR swizzle q = (s&3) ^ ((r>>1)&3)  (R7-validated: 0 conflicts)
    auto stage = [&](int slot, int kt) {
        #pragma unroll
        for (int i = 0; i < 2; ++i) {
            const int s = tid + i * NTHREADS;     // 1024 slots: 256 rows x 4 chunks
            const int r = s >> 2;
            const int q = (s & 3) ^ ((r >> 1) & 3);
            if constexpr (MODE == 2) {
                gload_lds16(apc + (size_t)(d0 + r) * D_SZ + kt * BK + q * 8,
                            aLds + slot * A_BUF + s * 8);
            } else {
                const float* gp = Af + (size_t)(d0 + r) * D_SZ + kt * BK + q * 8;
                const f32x4 gg0 = *(const f32x4*)(diag + (size_t)c * D_SZ + kt * BK + q * 8);
                const f32x4 gg1 = *(const f32x4*)(diag + (size_t)c * D_SZ + kt * BK + q * 8 + 4);
                const f32x4 a0 = *(const f32x4*)gp;
                const f32x4 a1 = *(const f32x4*)(gp + 4);
                short8 p;
                p[0]=(short)f2bf(a0.x/gg0.x); p[1]=(short)f2bf(a0.y/gg0.y);
                p[2]=(short)f2bf(a0.z/gg0.z); p[3]=(short)f2bf(a0.w/gg0.w);
                p[4]=(short)f2bf(a1.x/gg1.x); p[5]=(short)f2bf(a1.y/gg1.y);
                p[6]=(short)f2bf(a1.z/gg1.z); p[7]=(short)f2bf(a1.w/gg1.w);
                *(short8*)(aLds + slot * A_BUF + s * 8) = p;
            }
        }
        #pragma unroll
        for (int i = 0; i < 2; ++i) {
            const int s = tid + i * NTHREADS;
            const int r = s >> 2;
            const int q = (s & 3) ^ ((r >> 1) & 3);
            const int e = kt * BK + q * 8;
            if constexpr (MODE == 2) {
                gload_lds16(rbAll + (size_t)(b0 + r) * D_SZ + e,
                            xLds + slot * X_BUF + s * 8);
            } else {
                const float* rp = raw + (size_t)(b0 + r) * D_SZ + e;
                const f32x4 r0 = *(const f32x4*)rp, r1 = *(const f32x4*)(rp + 4);
                const f32x4 mm0 = *(const f32x4*)(mean + (size_t)c * D_SZ + e);
                const f32x4 mm1 = *(const f32x4*)(mean + (size_t)c * D_SZ + e + 4);
                const f32x4 gg0 = *(const f32x4*)(diag + (size_t)c * D_SZ + e);
                const f32x4 gg1 = *(const f32x4*)(diag + (size_t)c * D_SZ + e + 4);
                short8 p;
                p[0]=(short)f2bf((r0.x-mm0.x)/gg0.x); p[1]=(short)f2bf((r0.y-mm0.y)/gg0.y);
                p[2]=(short)f2bf((r0.z-mm0.z)/gg0.z); p[3]=(short)f2bf((r0.w-mm0.w)/gg0.w);
                p[4]=(short)f2bf((r1.x-mm1.x)/gg1.x); p[5]=(short)f2bf((r1.y-mm1.y)/gg1.y);
                p[6]=(short)f2bf((r1.z-mm1.z)/gg1.z); p[7]=(short)f2bf((r1.w-mm1.w)/gg1.w);
                *(short8*)(xLds + slot * X_BUF + s * 8) = p;
            }
        }
    };

    f32x4 acc[MF][NF] = {};   // wave 128(M) x 64(N)

    // frag chunk: row = 16a + l15 with (16a>>1)&3 == 0  ->  fch lane-constant
    const int fch = l4 ^ ((l15 >> 1) & 3);

    auto compute = [&](int slot) {
        const ushort* ab = aLds + slot * A_BUF;
        const ushort* xb = xLds + slot * X_BUF;
        short8 xf[NF];
        #pragma unroll
        for (int n = 0; n < NF; ++n)
            xf[n] = *(const short8*)(xb + ((wn * 64 + n * 16 + l15) * 4 + fch) * 8);
        __builtin_amdgcn_s_setprio(1);
        #pragma unroll
        for (int m = 0; m < MF; ++m) {
            const short8 af = *(const short8*)(ab + ((wm * 128 + m * 16 + l15) * 4 + fch) * 8);
            #pragma unroll
            for (int n = 0; n < NF; ++n)
                acc[m][n] = __builtin_amdgcn_mfma_f32_16x16x32_bf16(af, xf[n], acc[m][n], 0, 0, 0);
        }
        __builtin_amdgcn_s_setprio(0);
    };

    // prologue: 2 K-slabs in flight
    stage(0, 0);
    stage(1, 1);

    for (int kt = 0; kt < NKT; ++kt) {
        if constexpr (MODE == 2) {
            // counted drain: kt's 4 loads are the oldest; kt+1's 4 stay in flight
            if (kt < NKT - 1) asm volatile("s_waitcnt vmcnt(4)" ::: "memory");
            else              asm volatile("s_waitcnt vmcnt(0)" ::: "memory");
            __builtin_amdgcn_s_barrier();
        } else {
            __syncthreads();
        }
        if (kt + 2 < NKT) stage((kt + 2) % 3, kt + 2);   // writes slot (kt-1)%3: WAR-safe past barrier
        compute(kt % 3);
    }

    // ---- fold: v[n] = sum over block d-range of G[d,b]*x[b,d], x in f32 ----
    // C/D layout (validated): col(b)=l15, row(d)=l4*4+j
    float v[NF] = {};
    #pragma unroll
    for (int m = 0; m < MF; ++m) {
        const int dd = d0 + wm * 128 + m * 16 + l4 * 4;
        f32x4 rd4, md4;
        if constexpr (MODE == 2) {
            rd4 = *(const f32x4*)(rdT + (size_t)c * D_SZ + dd);
            md4 = *(const f32x4*)(mdT + (size_t)c * D_SZ + dd);
        } else {
            const f32x4 mm4 = *(const f32x4*)(mean + (size_t)c * D_SZ + dd);
            const f32x4 gg4 = *(const f32x4*)(diag + (size_t)c * D_SZ + dd);
            rd4.x = 1.0f/gg4.x; rd4.y = 1.0f/gg4.y; rd4.z = 1.0f/gg4.z; rd4.w = 1.0f/gg4.w;
            md4.x = mm4.x*rd4.x; md4.y = mm4.y*rd4.y; md4.z = mm4.z*rd4.z; md4.w = mm4.w*rd4.w;
        }
        #pragma unroll
        for (int n = 0; n < NF; ++n) {
            const int bl = b0 + wn * 64 + n * 16 + l15;
            const f32x4 rv = *(const f32x4*)(raw + (size_t)bl * D_SZ + dd);
            v[n] += acc[m][n][0] * (rv.x * rd4.x - md4.x)
                  + acc[m][n][1] * (rv.y * rd4.y - md4.y)
                  + acc[m][n][2] * (rv.z * rd4.z - md4.z)
                  + acc[m][n][3] * (rv.w * rd4.w - md4.w);
        }
    }
    #pragma unroll
    for (int n = 0; n < NF; ++n) {
        v[n] += __shfl_xor(v[n], 16);
        v[n] += __shfl_xor(v[n], 32);
    }
    if (lane < 16) {
        #pragma unroll
        for (int n = 0; n < NF; ++n) red[wid * 64 + n * 16 + l15] = v[n];
    }
    __syncthreads();
    if (tid < BN) {
        const int wno = tid >> 6;
        const int off = tid & 63;
        const float p = red[wno * 64 + off] + red[(4 + wno) * 64 + off];
        atomicAdd(out + (size_t)(b0 + tid) * C_SZ + c, -p);
    }
}

extern "C" void kernel_launch(void* const* d_in, const int* in_sizes, int n_in,
                              void* d_out, int out_size, void* d_ws, size_t ws_size,
                              hipStream_t stream) {
    const float* raw  = (const float*)d_in[0];
    const float* mean = (const float*)d_in[1];
    const float* inv  = (const float*)d_in[2];
    const float* diag = (const float*)d_in[3];
    float* out = (float*)d_out;

    const size_t TBL_B = TBL_ELEMS * 4;                    // 307,200
    const size_t AP_B  = AP_ELEMS * 2;                     // 117,964,800
    const size_t RB_B  = RB_ELEMS * 2;                     //   1,572,864
    const size_t need  = 3 * TBL_B + AP_B + RB_B;          // ~120.5 MB

    dim3 grid(8 * 13 * TPC);                               // 1248

    if (ws_size >= need) {
        float*  rdT = (float*)d_ws;
        float*  mdT = (float*)((char*)d_ws + TBL_B);
        float*  wT  = (float*)((char*)d_ws + 2 * TBL_B);
        ushort* ap  = (ushort*)((char*)d_ws + 3 * TBL_B);
        ushort* rb  = (ushort*)((char*)d_ws + 3 * TBL_B + AP_B);
        make_tables<<<75, 256, 0, stream>>>(mean, diag, rdT, mdT);
        conv_rawbf<<<384, 256, 0, stream>>>(raw, rb);
        conv_aprime<<<9600, 512, 0, stream>>>(inv, rdT, mdT, ap, wT);
        seed_out<<<400, 256, 0, stream>>>(raw, rdT, mdT, wT, out);
        fecam_scores<2><<<grid, NTHREADS, 0, stream>>>(raw, mean, diag, inv,
                                                       rdT, mdT, ap, rb, out);
    } else {
        hipMemsetAsync(d_out, 0, (size_t)out_size * sizeof(float), stream);
        fecam_scores<0><<<grid, NTHREADS, 0, stream>>>(raw, mean, diag, inv,
                                                       nullptr, nullptr, nullptr, nullptr, out);
    }
}

// Round 9
// 247.023 us; speedup vs baseline: 1.6024x; 1.2426x over previous
//
#include <hip/hip_runtime.h>
#include <hip/hip_bf16.h>

#define B_SZ 1024
#define C_SZ 100
#define D_SZ 768

#define BM 128                 // d-rows per block (M)
#define BN 128                 // b-cols per block (N)
#define BK 64                  // e per K-step
#define NKT (D_SZ / BK)        // 12
#define NTHREADS 256           // 4 waves: 2(M) x 2(N), wave tile 64x64
#define TPC 48                 // tiles/class: 6 M x 8 N

#define A_BUF (BM * BK)        // 8192 ushorts = 16 KB per buffer
#define X_BUF (BN * BK)

#define TBL_ELEMS ((size_t)C_SZ * D_SZ)          // 76,800
#define AP_ELEMS  ((size_t)C_SZ * D_SZ * D_SZ)   // 58,982,400
#define RB_ELEMS  ((size_t)B_SZ * D_SZ)          // 786,432

typedef float f32x4 __attribute__((ext_vector_type(4)));
typedef short short8 __attribute__((ext_vector_type(8)));

__device__ __forceinline__ ushort f2bf(float f) {
    union { __hip_bfloat16 b; ushort u; } cv; cv.b = __float2bfloat16(f); return cv.u;
}
__device__ __forceinline__ float bf2f(ushort u) {
    union { __hip_bfloat16 b; ushort us; } cv; cv.us = u; return __bfloat162float(cv.b);
}
__device__ __forceinline__ void gload_lds16(const void* g, void* l) {
    __builtin_amdgcn_global_load_lds((const __attribute__((address_space(1))) void*)g,
                                     (__attribute__((address_space(3))) void*)l, 16, 0, 0);
}

// ---- prepass 1: rd = 1/diag, md = mean*rd ----
__global__ __launch_bounds__(256) void make_tables(const float* __restrict__ mean,
                                                   const float* __restrict__ diag,
                                                   float* __restrict__ rd,
                                                   float* __restrict__ md) {
    const int i = ((int)blockIdx.x * 256 + (int)threadIdx.x) * 4;
    if (i < (int)TBL_ELEMS) {
        const f32x4 dv = *(const f32x4*)(diag + i);
        const f32x4 mv = *(const f32x4*)(mean + i);
        f32x4 r, m;
        r.x = 1.0f / dv.x; r.y = 1.0f / dv.y; r.z = 1.0f / dv.z; r.w = 1.0f / dv.w;
        m.x = mv.x * r.x;  m.y = mv.y * r.y;  m.z = mv.z * r.z;  m.w = mv.w * r.w;
        *(f32x4*)(rd + i) = r;
        *(f32x4*)(md + i) = m;
    }
}

// ---- prepass 2: rawbf = bf16(raw) ----
__global__ __launch_bounds__(256) void conv_rawbf(const float* __restrict__ raw,
                                                  ushort* __restrict__ rb) {
    const size_t i = (size_t)blockIdx.x * 256 + threadIdx.x;
    const f32x4 v0 = *(const f32x4*)(raw + i * 8);
    const f32x4 v1 = *(const f32x4*)(raw + i * 8 + 4);
    short8 p;
    p[0]=(short)f2bf(v0.x); p[1]=(short)f2bf(v0.y); p[2]=(short)f2bf(v0.z); p[3]=(short)f2bf(v0.w);
    p[4]=(short)f2bf(v1.x); p[5]=(short)f2bf(v1.y); p[6]=(short)f2bf(v1.z); p[7]=(short)f2bf(v1.w);
    *(short8*)(rb + i * 8) = p;
}

// ---- prepass 3: A'[c][d][e] = bf16(A*rd_c[e]); w[c][d] = dot(A_row, md_c) ----
__global__ __launch_bounds__(512) void conv_aprime(const float* __restrict__ inv,
                                                   const float* __restrict__ rd,
                                                   const float* __restrict__ md,
                                                   ushort* __restrict__ ap,
                                                   float* __restrict__ w) {
    const int lane = (int)threadIdx.x & 63;
    const int wv   = (int)threadIdx.x >> 6;
    const int ridx = (int)blockIdx.x * 8 + wv;            // c*768+d
    const int c    = ridx / D_SZ;
    const float* arow = inv + (size_t)ridx * D_SZ;
    const float* rdc  = rd + (size_t)c * D_SZ;
    const float* mdc  = md + (size_t)c * D_SZ;
    ushort* aprow = ap + (size_t)ridx * D_SZ;
    float dot = 0.f;
    #pragma unroll
    for (int j = 0; j < 3; ++j) {
        const int e = j * 256 + lane * 4;
        const f32x4 a  = *(const f32x4*)(arow + e);
        const f32x4 r4 = *(const f32x4*)(rdc + e);
        const f32x4 m4 = *(const f32x4*)(mdc + e);
        dot += a.x * m4.x + a.y * m4.y + a.z * m4.z + a.w * m4.w;
        ushort4 p;
        p.x = f2bf(a.x * r4.x); p.y = f2bf(a.y * r4.y);
        p.z = f2bf(a.z * r4.z); p.w = f2bf(a.w * r4.w);
        *(ushort4*)(aprow + e) = p;
    }
    #pragma unroll
    for (int k = 1; k < 64; k <<= 1) dot += __shfl_xor(dot, k);
    if (lane == 0) w[ridx] = dot;
}

// MODE 2: A'/rawbf via gload_lds; out += sum_d xfold[b,d]*(w[d] - t[d,b])
//         (algebra: = -dist including both cross terms; no seed kernel)
// MODE 0: no-ws fallback: reg-staged A bf16 + xn on the fly; out += -sum xn*t
template <int MODE>
__global__ __launch_bounds__(NTHREADS, 2) void fecam_scores(
        const float* __restrict__ raw, const float* __restrict__ mean,
        const float* __restrict__ diag, const float* __restrict__ inv,
        const float* __restrict__ rdT, const float* __restrict__ mdT,
        const float* __restrict__ wT,
        const ushort* __restrict__ apAll, const ushort* __restrict__ rbAll,
        float* __restrict__ out) {
    __shared__ __align__(16) ushort aLds[2 * A_BUF];   // 32 KB
    __shared__ __align__(16) ushort xLds[2 * X_BUF];   // 32 KB
    __shared__ float red[4 * 64];                      //  1 KB

    const int tid = (int)threadIdx.x;
    const int bx  = (int)blockIdx.x;

    // XCD-pinned class grouping (validated R3: A' read from HBM ~once)
    const int x = bx & 7;
    const int slot0 = bx >> 3;
    const int nCls  = (x < 4) ? 13 : 12;
    const int baseC = (x < 4) ? x * 13 : 52 + (x - 4) * 12;
    const int ci = slot0 / TPC;
    if (ci >= nCls) return;
    const int t  = slot0 % TPC;
    const int c  = baseC + ci;
    const int d0 = (t >> 3) * BM;      // 0..5
    const int b0 = (t & 7) * BN;       // 0..7

    const int lane = tid & 63;
    const int wid  = tid >> 6;
    const int wm   = wid >> 1;         // 0..1 (M)
    const int wn   = wid & 1;          // 0..1 (N)
    const int l15  = lane & 15;
    const int l4   = lane >> 4;

    const ushort* apc = apAll + (size_t)c * D_SZ * D_SZ;
    const float*  Af  = inv + (size_t)c * D_SZ * D_SZ;

    // staging: source-side XOR swizzle q = (s&7) ^ (r&7); LDS dest linear.
    // rows are 128B (=32 banks) apart -> read conflicts resolved by the q XOR:
    // per 16-lane phase each 16B slot is hit by exactly 2 lanes (free, m136).
    auto stage = [&](int buf, int kt) {
        #pragma unroll
        for (int i = 0; i < 4; ++i) {
            const int s = tid + i * NTHREADS;   // 1024 slots: 128 rows x 8 chunks
            const int r = s >> 3;
            const int q = (s & 7) ^ (r & 7);
            if constexpr (MODE == 2) {
                gload_lds16(apc + (size_t)(d0 + r) * D_SZ + kt * BK + q * 8,
                            aLds + buf * A_BUF + s * 8);
            } else {
                const float* gp = Af + (size_t)(d0 + r) * D_SZ + kt * BK + q * 8;
                const f32x4 a0 = *(const f32x4*)gp;
                const f32x4 a1 = *(const f32x4*)(gp + 4);
                short8 p;
                p[0]=(short)f2bf(a0.x); p[1]=(short)f2bf(a0.y); p[2]=(short)f2bf(a0.z); p[3]=(short)f2bf(a0.w);
                p[4]=(short)f2bf(a1.x); p[5]=(short)f2bf(a1.y); p[6]=(short)f2bf(a1.z); p[7]=(short)f2bf(a1.w);
                *(short8*)(aLds + buf * A_BUF + s * 8) = p;
            }
        }
        #pragma unroll
        for (int i = 0; i < 4; ++i) {
            const int s = tid + i * NTHREADS;
            const int r = s >> 3;
            const int q = (s & 7) ^ (r & 7);
            const int e = kt * BK + q * 8;
            if constexpr (MODE == 2) {
                gload_lds16(rbAll + (size_t)(b0 + r) * D_SZ + e,
                            xLds + buf * X_BUF + s * 8);
            } else {
                const float* rp = raw + (size_t)(b0 + r) * D_SZ + e;
                const f32x4 r0 = *(const f32x4*)rp, r1 = *(const f32x4*)(rp + 4);
                const f32x4 mm0 = *(const f32x4*)(mean + (size_t)c * D_SZ + e);
                const f32x4 mm1 = *(const f32x4*)(mean + (size_t)c * D_SZ + e + 4);
                const f32x4 gg0 = *(const f32x4*)(diag + (size_t)c * D_SZ + e);
                const f32x4 gg1 = *(const f32x4*)(diag + (size_t)c * D_SZ + e + 4);
                short8 p;
                p[0]=(short)f2bf((r0.x-mm0.x)/gg0.x); p[1]=(short)f2bf((r0.y-mm0.y)/gg0.y);
                p[2]=(short)f2bf((r0.z-mm0.z)/gg0.z); p[3]=(short)f2bf((r0.w-mm0.w)/gg0.w);
                p[4]=(short)f2bf((r1.x-mm1.x)/gg1.x); p[5]=(short)f2bf((r1.y-mm1.y)/gg1.y);
                p[6]=(short)f2bf((r1.z-mm1.z)/gg1.z); p[7]=(short)f2bf((r1.w-mm1.w)/gg1.w);
                *(short8*)(xLds + buf * X_BUF + s * 8) = p;
            }
        }
    };

    f32x4 acc[4][4] = {};   // wave 64(M) x 64(N)

    auto compute = [&](int buf) {
        const ushort* ab = aLds + buf * A_BUF;
        const ushort* xb = xLds + buf * X_BUF;
        #pragma unroll
        for (int kk = 0; kk < 2; ++kk) {
            const int fc = (kk * 4 + l4) ^ (l15 & 7);   // matches source swizzle
            short8 xf[4];
            #pragma unroll
            for (int n = 0; n < 4; ++n)
                xf[n] = *(const short8*)(xb + (wn * 64 + n * 16 + l15) * 64 + fc * 8);
            __builtin_amdgcn_s_setprio(1);
            #pragma unroll
            for (int m = 0; m < 4; ++m) {
                const short8 af = *(const short8*)(ab + (wm * 64 + m * 16 + l15) * 64 + fc * 8);
                #pragma unroll
                for (int n = 0; n < 4; ++n)
                    acc[m][n] = __builtin_amdgcn_mfma_f32_16x16x32_bf16(af, xf[n], acc[m][n], 0, 0, 0);
            }
            __builtin_amdgcn_s_setprio(0);
        }
    };

    stage(0, 0);
    __syncthreads();
    for (int kt = 0; kt < NKT; ++kt) {
        const int cur = kt & 1;
        if (kt + 1 < NKT) stage(cur ^ 1, kt + 1);   // overlaps compute; drained at sync
        compute(cur);
        __syncthreads();
    }

    // ---- fold: v[n] = sum_{d in range} xfold[b,d] * (w[d] - t[d,b]) ----
    // C/D layout (validated): col(b)=l15, row(d)=l4*4+j
    float v[4] = {};
    #pragma unroll
    for (int m = 0; m < 4; ++m) {
        const int dd = d0 + wm * 64 + m * 16 + l4 * 4;
        f32x4 rd4, md4, w4;
        if constexpr (MODE == 2) {
            rd4 = *(const f32x4*)(rdT + (size_t)c * D_SZ + dd);
            md4 = *(const f32x4*)(mdT + (size_t)c * D_SZ + dd);
            w4  = *(const f32x4*)(wT + (size_t)c * D_SZ + dd);
        } else {
            const f32x4 mm4 = *(const f32x4*)(mean + (size_t)c * D_SZ + dd);
            const f32x4 gg4 = *(const f32x4*)(diag + (size_t)c * D_SZ + dd);
            rd4.x = 1.0f/gg4.x; rd4.y = 1.0f/gg4.y; rd4.z = 1.0f/gg4.z; rd4.w = 1.0f/gg4.w;
            md4.x = mm4.x*rd4.x; md4.y = mm4.y*rd4.y; md4.z = mm4.z*rd4.z; md4.w = mm4.w*rd4.w;
            w4.x = 0.f; w4.y = 0.f; w4.z = 0.f; w4.w = 0.f;   // MODE0: pure -dist form
        }
        #pragma unroll
        for (int n = 0; n < 4; ++n) {
            const int bl = b0 + wn * 64 + n * 16 + l15;
            const f32x4 rv = *(const f32x4*)(raw + (size_t)bl * D_SZ + dd);
            v[n] += (w4.x - acc[m][n][0]) * (rv.x * rd4.x - md4.x)
                  + (w4.y - acc[m][n][1]) * (rv.y * rd4.y - md4.y)
                  + (w4.z - acc[m][n][2]) * (rv.z * rd4.z - md4.z)
                  + (w4.w - acc[m][n][3]) * (rv.w * rd4.w - md4.w);
        }
    }
    #pragma unroll
    for (int n = 0; n < 4; ++n) {
        v[n] += __shfl_xor(v[n], 16);
        v[n] += __shfl_xor(v[n], 32);
    }
    if (lane < 16) {
        #pragma unroll
        for (int n = 0; n < 4; ++n) red[wid * 64 + n * 16 + l15] = v[n];
    }
    __syncthreads();
    if (tid < BN) {
        const int wnn = tid >> 6;          // which wn column-half
        const int off = tid & 63;
        const float p = red[wnn * 64 + off] + red[(wnn + 2) * 64 + off];
        atomicAdd(out + (size_t)(b0 + tid) * C_SZ + c, p);
    }
}

extern "C" void kernel_launch(void* const* d_in, const int* in_sizes, int n_in,
                              void* d_out, int out_size, void* d_ws, size_t ws_size,
                              hipStream_t stream) {
    const float* raw  = (const float*)d_in[0];
    const float* mean = (const float*)d_in[1];
    const float* inv  = (const float*)d_in[2];
    const float* diag = (const float*)d_in[3];
    float* out = (float*)d_out;

    const size_t TBL_B = TBL_ELEMS * 4;                    // 307,200
    const size_t AP_B  = AP_ELEMS * 2;                     // 117,964,800
    const size_t RB_B  = RB_ELEMS * 2;                     //   1,572,864
    const size_t need  = 3 * TBL_B + AP_B + RB_B;          // ~120.5 MB

    hipMemsetAsync(d_out, 0, (size_t)out_size * sizeof(float), stream);
    dim3 grid(8 * 13 * TPC);                               // 4992

    if (ws_size >= need) {
        float*  rdT = (float*)d_ws;
        float*  mdT = (float*)((char*)d_ws + TBL_B);
        float*  wT  = (float*)((char*)d_ws + 2 * TBL_B);
        ushort* ap  = (ushort*)((char*)d_ws + 3 * TBL_B);
        ushort* rb  = (ushort*)((char*)d_ws + 3 * TBL_B + AP_B);
        make_tables<<<75, 256, 0, stream>>>(mean, diag, rdT, mdT);
        conv_rawbf<<<384, 256, 0, stream>>>(raw, rb);
        conv_aprime<<<9600, 512, 0, stream>>>(inv, rdT, mdT, ap, wT);
        fecam_scores<2><<<grid, NTHREADS, 0, stream>>>(raw, mean, diag, inv,
                                                       rdT, mdT, wT, ap, rb, out);
    } else {
        fecam_scores<0><<<grid, NTHREADS, 0, stream>>>(raw, mean, diag, inv,
                                                       nullptr, nullptr, nullptr,
                                                       nullptr, nullptr, out);
    }
}